// Round 12
// baseline (55.002 us; speedup 1.0000x reference)
//
#include <hip/hip_runtime.h>
#include <math.h>

#define BATCH 16
#define CHN   16
#define IMH   96
#define IMW   320
#define HW    (IMH*IMW)          /* 30720 */
#define PPB   128                /* points per block (2 half-threads each) */
#define NBLK  (HW/PPB)           /* 240 blocks per batch */
#define NPART 27                 /* 21 (sym H) + 6 (b) */
#define TWB   (HW*4)             /* tgt_w corner-record bytes per batch */
#define RECB  (HW*16)            /* fp4 record map bytes per batch */

typedef __attribute__((ext_vector_type(2))) float f32x2;

// 4-step DPP row reduce (row_shr 1/2/4/8): lane 15+16r holds the sum of its 16-lane row.
__device__ __forceinline__ float dpp_row_sum(float x) {
    union fi { float f; int i; };
    fi v; v.f = x;
#define DPPSTEP(CTRL) { fi t; t.i = __builtin_amdgcn_update_dpp(0, v.i, CTRL, 0xf, 0xf, true); v.f += t.f; }
    DPPSTEP(0x111)
    DPPSTEP(0x112)
    DPPSTEP(0x114)
    DPPSTEP(0x118)
#undef DPPSTEP
    return v.f;
}

// ---- kernel 0: quantize tgt_feat to fp4 records (dword-interleaved); tgt_w 4-corner dwords ----
// Record (x,y), 16B, dwords: [p(x,y).d0, p(x,y+1).d0, p(x,y).d1, p(x,y+1).d1]
// (dK = 8 channels K*8..K*8+7 packed fp4). Half-thread h reads int2 at +h*8.
__global__ __launch_bounds__(256) void build_maps(const float* __restrict__ in,
                                                  const float* __restrict__ tw,
                                                  char* __restrict__ rec,
                                                  char* __restrict__ twr) {
    const int b = blockIdx.y;
    const int p = blockIdx.x * 256 + threadIdx.x;
    const int y = p / IMW, x = p - y * IMW;
    const float* ip = in + (size_t)b * CHN * HW + p;
    float f[16];
#pragma unroll
    for (int c = 0; c < 16; ++c) f[c] = ip[c * HW];

    unsigned d0 = 0, d1 = 0;
    d0 = __builtin_amdgcn_cvt_scalef32_pk_fp4_f32(d0, f[0],  f[1],  1.0f, 0);
    d0 = __builtin_amdgcn_cvt_scalef32_pk_fp4_f32(d0, f[2],  f[3],  1.0f, 1);
    d0 = __builtin_amdgcn_cvt_scalef32_pk_fp4_f32(d0, f[4],  f[5],  1.0f, 2);
    d0 = __builtin_amdgcn_cvt_scalef32_pk_fp4_f32(d0, f[6],  f[7],  1.0f, 3);
    d1 = __builtin_amdgcn_cvt_scalef32_pk_fp4_f32(d1, f[8],  f[9],  1.0f, 0);
    d1 = __builtin_amdgcn_cvt_scalef32_pk_fp4_f32(d1, f[10], f[11], 1.0f, 1);
    d1 = __builtin_amdgcn_cvt_scalef32_pk_fp4_f32(d1, f[12], f[13], 1.0f, 2);
    d1 = __builtin_amdgcn_cvt_scalef32_pk_fp4_f32(d1, f[14], f[15], 1.0f, 3);

    int* rb = (int*)(rec + (size_t)b * RECB);
    const int self = p * 4;              // dword index of own record
    rb[self + 0] = (int)d0;              // own row0.d0
    rb[self + 2] = (int)d1;              // own row0.d1
    if (y > 0) {
        const int up = (p - IMW) * 4;    // record above: we are its row1
        rb[up + 1] = (int)d0;
        rb[up + 3] = (int)d1;
    }
    if (y == IMH - 1) {                  // clamp: own record's row1 = self
        rb[self + 1] = (int)d0;
        rb[self + 3] = (int)d1;
    }

    const float* twb = tw + (size_t)b * HW;
    const int xp1 = min(x + 1, IMW - 1), yp1 = min(y + 1, IMH - 1);
    const float v00 = twb[p];
    const float v01 = twb[y * IMW + xp1];
    const float v10 = twb[yp1 * IMW + x];
    const float v11 = twb[yp1 * IMW + xp1];
    int wq = __builtin_amdgcn_cvt_pk_fp8_f32(v00, v01, 0, false);
    wq     = __builtin_amdgcn_cvt_pk_fp8_f32(v10, v11, wq, true);
    ((int*)(twr + (size_t)b * TWB))[p] = wq;
}

// ---- kernel 1: 2 half-threads per point (8 channels each), per-block partial H/b ----
__global__ __launch_bounds__(256, 2) void gn_accum(
    const float* __restrict__ p2,
    const float* __restrict__ P2,
    const float* __restrict__ calibK,
    const float* __restrict__ weight,
    const float* __restrict__ src_feat,
    const float* __restrict__ src_w,
    const char* __restrict__ twr,
    const char* __restrict__ rec,
    float* __restrict__ partials)        // (B, NBLK, NPART)
{
    __shared__ float xs_l[768];
    __shared__ float ys_l[768];
    __shared__ float red[16][NPART];

    // XCD pinning: XCD k serves batches {k, k+8}
    const int n   = blockIdx.x;
    const int b   = n & 15;
    const int blk = n >> 4;
    const int t   = threadIdx.x;
    const int m   = t >> 1;              // point within block (0..127)
    const int h   = t & 1;               // channel half (0: ch0-7, 1: ch8-15)
    const int pp  = blk * PPB + m;       // global point in batch

    // ---- cooperative coalesced stage of the block's 640 grid coords ----
    const unsigned Gblk0 = ((unsigned)b * HW + (unsigned)(blk * PPB)) * 5u;
#pragma unroll
    for (int j = 0; j < 3; ++j) {
        const unsigned idx = (unsigned)(j * 256 + t);
        if (idx < 640) {
            const unsigned G    = Gblk0 + idx;
            const unsigned sBig = G / (unsigned)(BATCH * HW);
            const unsigned r    = G - sBig * (unsigned)(BATCH * HW);
            const unsigned bb   = r / (unsigned)HW;
            const unsigned q    = r - bb * (unsigned)HW;
            const float* pb = p2 + (size_t)bb * (10 * HW) + (size_t)sBig * HW + q;
            xs_l[idx] = pb[0];
            ys_l[idx] = pb[5 * HW];
        }
    }
    __syncthreads();

    // ---- per-point sample geometry (computed by both halves) ----
    float wxs[5], wys[5];
    int   off[5];
    int   twoff = 0;
#pragma unroll
    for (int s = 0; s < 5; ++s) {
        const float xp = xs_l[5 * m + s];
        const float yp = ys_l[5 * m + s];
        float gx = 2.0f * (xp + 0.5f) / (float)IMW - 1.0f;
        float gy = 2.0f * (yp + 0.5f) / (float)IMH - 1.0f;
        float x  = (gx + 1.0f) * ((float)IMW * 0.5f) - 0.5f;
        float y  = (gy + 1.0f) * ((float)IMH * 0.5f) - 0.5f;
        float x0 = floorf(x), y0 = floorf(y);
        wxs[s] = x - x0;
        wys[s] = y - y0;
        int xi = (int)x0, yi = (int)y0;
        xi = min(max(xi, 0), IMW - 2);
        yi = min(max(yi, 0), IMH - 2);
        off[s] = (yi * IMW + xi) * 16;
        if (s == 0) twoff = (yi * IMW + xi) * 4;
    }

    // ---- issue all scattered loads up front: 10 int2 gathers + twq ----
    // L0[s] = {row0,row1} dwords of record x0 for half h; L1[s] = same at x0+1.
    const char* mapb = rec + (size_t)b * RECB + h * 8;
    int2 L0[5], L1[5];
#pragma unroll
    for (int s = 0; s < 5; ++s) {
        L0[s] = *(const int2*)(mapb + off[s]);
        L1[s] = *(const int2*)(mapb + off[s] + 16);
    }
    const int twq = *(const int*)(twr + (size_t)b * TWB + twoff);

    // 8 coalesced src dwords for this half
    float srcv[8];
    const float* srcb = src_feat + (size_t)b * CHN * HW + (size_t)h * 8 * HW + pp;
#pragma unroll
    for (int j = 0; j < 8; ++j) srcv[j] = srcb[j * HW];

    const float* P2b = P2 + (size_t)b * 3 * HW;
    const float X = P2b[pp], Y = P2b[HW + pp], Z = P2b[2 * HW + pp];
    const float wP  = weight[(size_t)b * HW + pp];
    const float swP = src_w[(size_t)b * HW + pp];

    // ---- latency fill: Jacobian rows + corner weights (duplicated per half) ----
    const float fx = calibK[b * 9 + 0];
    const float fy = calibK[b * 9 + 4];
    const float fxZ = fx / Z, fyZ = fy / Z;
    const float fxXZ2 = fxZ * X / Z;
    const float fyYZ2 = fyZ * Y / Z;
    float r0[6] = { fxZ, 0.0f, -fxXZ2, -fxXZ2 * Y, fx + fxXZ2 * X, -fxZ * Y };
    float r1[6] = { 0.0f, fyZ, -fyYZ2, -fy - fyYZ2 * Y, fyYZ2 * X, fyZ * X };

    float w00[5], w01[5], w10[5], w11[5];
#pragma unroll
    for (int s = 0; s < 5; ++s) {
        float wx = wxs[s], wy = wys[s];
        w00[s] = (1.0f - wx) * (1.0f - wy);
        w01[s] = wx * (1.0f - wy);
        w10[s] = (1.0f - wx) * wy;
        w11[s] = wx * wy;
    }

    float wtw;
    {
        const float wx = wxs[0], wy = wys[0];
        f32x2 wlo = __builtin_amdgcn_cvt_pk_f32_fp8(twq, false);
        f32x2 whi = __builtin_amdgcn_cvt_pk_f32_fp8(twq, true);
        wtw = wlo[0] * (1.0f - wx) * (1.0f - wy) + wlo[1] * wx * (1.0f - wy)
            + whi[0] * (1.0f - wx) * wy          + whi[1] * wx * wy;
    }
    const float w = swP * wtw * wP;

    // ---- decode fp4 + bilinear mix + half-channel moments ----
    f32x2 SxxV = {0.f,0.f}, SxyV = {0.f,0.f}, SyyV = {0.f,0.f}, TxV = {0.f,0.f}, TyV = {0.f,0.f};
#define PAIRSTEP(K) {                                                             \
        f32x2 fsv[5];                                                             \
        _Pragma("unroll")                                                         \
        for (int s = 0; s < 5; ++s) {                                             \
            fsv[s] = __builtin_amdgcn_cvt_scalef32_pk_f32_fp4(L0[s].x, 1.0f, K) * w00[s] \
                   + __builtin_amdgcn_cvt_scalef32_pk_f32_fp4(L1[s].x, 1.0f, K) * w01[s] \
                   + __builtin_amdgcn_cvt_scalef32_pk_f32_fp4(L0[s].y, 1.0f, K) * w10[s] \
                   + __builtin_amdgcn_cvt_scalef32_pk_f32_fp4(L1[s].y, 1.0f, K) * w11[s]; \
        }                                                                         \
        const f32x2 sr = { srcv[2 * (K)], srcv[2 * (K) + 1] };                    \
        f32x2 resv = sr - fsv[0];                                                 \
        f32x2 gxv  = (fsv[1] - fsv[2]) * 0.5f;                                    \
        f32x2 gyv  = (fsv[3] - fsv[4]) * 0.5f;                                    \
        SxxV += gxv * gxv; SxyV += gxv * gyv; SyyV += gyv * gyv;                  \
        TxV  += resv * gxv; TyV += resv * gyv; }
    PAIRSTEP(0) PAIRSTEP(1) PAIRSTEP(2) PAIRSTEP(3)
#undef PAIRSTEP

    const float Sxx = SxxV[0] + SxxV[1];
    const float Sxy = SxyV[0] + SxyV[1];
    const float Syy = SyyV[0] + SyyV[1];
    const float Tx  = TxV[0]  + TxV[1];
    const float Ty  = TyV[0]  + TyV[1];

    const float Pm = w * Sxx, Qm = w * Sxy, Rm = w * Syy;
    const float tx = w * Tx,  ty = w * Ty;

    // ---- rank-2 H: H(k,l) = r0[k]*a[l] + r1[k]*c[l]  (per half; additive) ----
    float av[6], cv[6];
#pragma unroll
    for (int k = 0; k < 6; ++k) {
        av[k] = Pm * r0[k] + Qm * r1[k];
        cv[k] = Qm * r0[k] + Rm * r1[k];
    }

    // ---- 27 values: 4-step DPP row sum -> 16 LDS rows -> block combine ----
    const int wv   = t >> 6;
    const int lane = t & 63;
    const int rrow = (wv << 2) | (lane >> 4);
    const bool wr  = (lane & 15) == 15;

    int idx = 0;
#pragma unroll
    for (int k = 0; k < 6; ++k) {
#pragma unroll
        for (int l = 0; l < 6; ++l) {
            if (l < k) continue;
            float v = r0[k] * av[l] + r1[k] * cv[l];
            v = dpp_row_sum(v);
            if (wr) red[rrow][idx] = v;
            ++idx;
        }
    }
#pragma unroll
    for (int k = 0; k < 6; ++k) {
        float v = tx * r0[k] + ty * r1[k];
        v = dpp_row_sum(v);
        if (wr) red[rrow][21 + k] = v;
    }
    __syncthreads();
    if (t < NPART) {
        float s = 0.0f;
#pragma unroll
        for (int r = 0; r < 16; ++r) s += red[r][t];
        partials[((size_t)b * NBLK + blk) * NPART + t] = s;
    }
}

// ---------------- kernel 2: double reduce + solve + se3_exp + compose ----------------
__global__ __launch_bounds__(256) void gn_solve(
    const float* __restrict__ partials,
    const float* __restrict__ poses,
    float* __restrict__ out)
{
    const int b = blockIdx.x;
    const int t = threadIdx.x;
    __shared__ double dsum[8][NPART];
    __shared__ double sums[NPART];

    if (t < 216) {
        const int col = t % NPART;
        const int g   = t / NPART;
        double s = 0.0;
        for (int j = g; j < NBLK; j += 8)
            s += (double)partials[((size_t)b * NBLK + j) * NPART + col];
        dsum[g][col] = s;
    }
    __syncthreads();
    if (t < NPART) {
        double s = 0.0;
#pragma unroll
        for (int g = 0; g < 8; ++g) s += dsum[g][t];
        sums[t] = s;
    }
    __syncthreads();
    if (t != 0) return;

    double A[6][7];
    {
        int idx = 0;
        for (int k = 0; k < 6; ++k)
            for (int l = k; l < 6; ++l) {
                A[k][l] = sums[idx];
                A[l][k] = sums[idx];
                ++idx;
            }
        for (int k = 0; k < 6; ++k) A[k][6] = sums[21 + k];
    }
    for (int col = 0; col < 6; ++col) {
        int piv = col; double mx = fabs(A[col][col]);
        for (int rr = col + 1; rr < 6; ++rr) {
            double v = fabs(A[rr][col]);
            if (v > mx) { mx = v; piv = rr; }
        }
        if (piv != col)
            for (int j = col; j < 7; ++j) { double tmp = A[col][j]; A[col][j] = A[piv][j]; A[piv][j] = tmp; }
        double d = A[col][col];
        for (int rr = col + 1; rr < 6; ++rr) {
            double f = A[rr][col] / d;
            for (int j = col; j < 7; ++j) A[rr][j] -= f * A[col][j];
        }
    }
    double x[6];
    for (int i = 5; i >= 0; --i) {
        double s = A[i][6];
        for (int j = i + 1; j < 6; ++j) s -= A[i][j] * x[j];
        x[i] = s / A[i][i];
    }

    const double rho[3] = { x[0], x[1], x[2] };
    const double phi[3] = { x[3], x[4], x[5] };
    const double th2 = phi[0]*phi[0] + phi[1]*phi[1] + phi[2]*phi[2];
    const bool small = th2 < 1e-8;
    const double th2s = small ? 1.0 : th2;
    const double th = sqrt(th2s);
    const double Ac = small ? 1.0 - th2 / 6.0   : sin(th) / th;
    const double Bc = small ? 0.5 - th2 / 24.0  : (1.0 - cos(th)) / th2s;
    const double Cc = small ? 1.0/6.0 - th2/120.0 : (th - sin(th)) / (th2s * th);
    const double Kh[3][3] = { { 0.0, -phi[2],  phi[1] },
                              {  phi[2], 0.0, -phi[0] },
                              { -phi[1],  phi[0], 0.0 } };
    double K2[3][3];
    for (int i = 0; i < 3; ++i)
        for (int j = 0; j < 3; ++j) {
            double s = 0.0;
            for (int k = 0; k < 3; ++k) s += Kh[i][k] * Kh[k][j];
            K2[i][j] = s;
        }
    double T[4][4];
    for (int i = 0; i < 3; ++i)
        for (int j = 0; j < 3; ++j) {
            double I = (i == j) ? 1.0 : 0.0;
            T[i][j] = I + Ac * Kh[i][j] + Bc * K2[i][j];
        }
    for (int i = 0; i < 3; ++i) {
        double s = 0.0;
        for (int j = 0; j < 3; ++j) {
            double I = (i == j) ? 1.0 : 0.0;
            double V = I + Bc * Kh[i][j] + Cc * K2[i][j];
            s += V * rho[j];
        }
        T[i][3] = s;
    }
    T[3][0] = 0.0; T[3][1] = 0.0; T[3][2] = 0.0; T[3][3] = 1.0;

    const float* pz = poses + b * 16;
    for (int i = 0; i < 4; ++i)
        for (int j = 0; j < 4; ++j) {
            double s = 0.0;
            for (int k = 0; k < 4; ++k) s += T[i][k] * (double)pz[k * 4 + j];
            out[b * 16 + i * 4 + j] = (float)s;
        }
    for (int k = 0; k < 6; ++k)
        out[BATCH * 16 + b * 6 + k] = (float)x[k];
}

extern "C" void kernel_launch(void* const* d_in, const int* in_sizes, int n_in,
                              void* d_out, int out_size, void* d_ws, size_t ws_size,
                              hipStream_t stream) {
    const float* poses    = (const float*)d_in[0];
    const float* calibK   = (const float*)d_in[1];
    const float* p2       = (const float*)d_in[2];
    const float* P2       = (const float*)d_in[3];
    const float* weight   = (const float*)d_in[4];
    const float* src_feat = (const float*)d_in[5];
    const float* tgt_feat = (const float*)d_in[6];
    const float* src_w    = (const float*)d_in[7];
    const float* tgt_w    = (const float*)d_in[8];
    float* out = (float*)d_out;

    char*  rec      = (char*)d_ws;                               // 16*RECB = 7.9 MB
    char*  twr      = rec + (size_t)BATCH * RECB;                // 16*TWB  = 2.0 MB
    float* partials = (float*)(twr + (size_t)BATCH * TWB);       // 0.7 MB  (total 10.5 MB)

    hipLaunchKernelGGL(build_maps, dim3(HW / 256, BATCH), dim3(256), 0, stream,
                       tgt_feat, tgt_w, rec, twr);
    hipLaunchKernelGGL(gn_accum, dim3(NBLK * BATCH), dim3(256), 0, stream,
                       p2, P2, calibK, weight, src_feat, src_w, twr, rec, partials);
    hipLaunchKernelGGL(gn_solve, dim3(BATCH), dim3(256), 0, stream,
                       partials, poses, out);
}

// Round 13
// 53.389 us; speedup vs baseline: 1.0302x; 1.0302x over previous
//
#include <hip/hip_runtime.h>
#include <math.h>

#define BATCH 16
#define CHN   16
#define IMH   96
#define IMW   320
#define HW    (IMH*IMW)          /* 30720 */
#define PPB   64                 /* points per block = 1 wave */
#define NSLOT (HW/PPB)           /* 480 blocks (slots) per batch */
#define NPART 27                 /* 21 (sym H) + 6 (b) */
#define TWB   (HW*4)             /* tgt_w corner-record bytes per batch */
#define RECB  (HW*16)            /* fp4 y-pair record map bytes per batch */

typedef __attribute__((ext_vector_type(2))) float f32x2;

// 4-step DPP row reduce (row_shr 1/2/4/8): lane 15+16r holds the sum of its 16-lane row.
__device__ __forceinline__ float dpp_row_sum(float x) {
    union fi { float f; int i; };
    fi v; v.f = x;
#define DPPSTEP(CTRL) { fi t; t.i = __builtin_amdgcn_update_dpp(0, v.i, CTRL, 0xf, 0xf, true); v.f += t.f; }
    DPPSTEP(0x111)
    DPPSTEP(0x112)
    DPPSTEP(0x114)
    DPPSTEP(0x118)
#undef DPPSTEP
    return v.f;
}

// ---- kernel 0: quantize tgt_feat to fp4 y-pair records; tgt_w 4-corner dwords ----
// Record (x,y), 16B: [pix(x,y) 8B fp4x16ch | pix(x,min(y+1,95)) 8B].
__global__ __launch_bounds__(256) void build_maps(const float* __restrict__ in,
                                                  const float* __restrict__ tw,
                                                  char* __restrict__ rec,
                                                  char* __restrict__ twr) {
    const int b = blockIdx.y;
    const int p = blockIdx.x * 256 + threadIdx.x;
    const int y = p / IMW, x = p - y * IMW;
    const float* ip = in + (size_t)b * CHN * HW + p;
    float f[16];
#pragma unroll
    for (int c = 0; c < 16; ++c) f[c] = ip[c * HW];

    unsigned d0 = 0, d1 = 0;
    d0 = __builtin_amdgcn_cvt_scalef32_pk_fp4_f32(d0, f[0],  f[1],  1.0f, 0);
    d0 = __builtin_amdgcn_cvt_scalef32_pk_fp4_f32(d0, f[2],  f[3],  1.0f, 1);
    d0 = __builtin_amdgcn_cvt_scalef32_pk_fp4_f32(d0, f[4],  f[5],  1.0f, 2);
    d0 = __builtin_amdgcn_cvt_scalef32_pk_fp4_f32(d0, f[6],  f[7],  1.0f, 3);
    d1 = __builtin_amdgcn_cvt_scalef32_pk_fp4_f32(d1, f[8],  f[9],  1.0f, 0);
    d1 = __builtin_amdgcn_cvt_scalef32_pk_fp4_f32(d1, f[10], f[11], 1.0f, 1);
    d1 = __builtin_amdgcn_cvt_scalef32_pk_fp4_f32(d1, f[12], f[13], 1.0f, 2);
    d1 = __builtin_amdgcn_cvt_scalef32_pk_fp4_f32(d1, f[14], f[15], 1.0f, 3);
    int2 lv; lv.x = (int)d0; lv.y = (int)d1;
    char* rb = rec + (size_t)b * RECB;
    *(int2*)(rb + (size_t)p * 16) = lv;                               // own record lo
    if (y > 0)        *(int2*)(rb + (size_t)(p - IMW) * 16 + 8) = lv; // record above, hi
    if (y == IMH - 1) *(int2*)(rb + (size_t)p * 16 + 8) = lv;         // clamp row

    const float* twb = tw + (size_t)b * HW;
    const int xp1 = min(x + 1, IMW - 1), yp1 = min(y + 1, IMH - 1);
    const float v00 = twb[p];
    const float v01 = twb[y * IMW + xp1];
    const float v10 = twb[yp1 * IMW + x];
    const float v11 = twb[yp1 * IMW + xp1];
    int wq = __builtin_amdgcn_cvt_pk_fp8_f32(v00, v01, 0, false);
    wq     = __builtin_amdgcn_cvt_pk_fp8_f32(v10, v11, wq, true);
    ((int*)(twr + (size_t)b * TWB))[p] = wq;
}

// ---- kernel 1: single-wave blocks, 1 point/thread, per-block partial H/b ----
__global__ __launch_bounds__(64, 4) void gn_accum(
    const float* __restrict__ p2,
    const float* __restrict__ P2,
    const float* __restrict__ calibK,
    const float* __restrict__ weight,
    const float* __restrict__ src_feat,
    const float* __restrict__ src_w,
    const char* __restrict__ twr,
    const char* __restrict__ rec,
    float* __restrict__ partials)        // (B, NPART, NSLOT) transposed
{
    __shared__ float xs_l[320];
    __shared__ float ys_l[320];
    __shared__ float red[4][NPART];

    // XCD pinning: XCD k serves batches {k, k+8}
    const int n   = blockIdx.x;
    const int b   = n & 15;
    const int blk = n >> 4;              // 0..479
    const int t   = threadIdx.x;         // lane 0..63
    const int p   = blk * PPB + t;

    // ---- cooperative coalesced stage of the block's 320 grid coords ----
    const unsigned Gblk0 = ((unsigned)b * HW + (unsigned)(blk * PPB)) * 5u;
#pragma unroll
    for (int j = 0; j < 5; ++j) {
        const unsigned idx  = (unsigned)(j * 64 + t);
        const unsigned G    = Gblk0 + idx;
        const unsigned sBig = G / (unsigned)(BATCH * HW);
        const unsigned r    = G - sBig * (unsigned)(BATCH * HW);
        const unsigned bb   = r / (unsigned)HW;
        const unsigned q    = r - bb * (unsigned)HW;
        const float* pb = p2 + (size_t)bb * (10 * HW) + (size_t)sBig * HW + q;
        xs_l[idx] = pb[0];
        ys_l[idx] = pb[5 * HW];
    }
    __syncthreads();

    // ---- per-point sample geometry from LDS ----
    float wxs[5], wys[5];
    int   off[5];
    int   twoff = 0;
#pragma unroll
    for (int s = 0; s < 5; ++s) {
        const float xp = xs_l[5 * t + s];
        const float yp = ys_l[5 * t + s];
        float gx = 2.0f * (xp + 0.5f) / (float)IMW - 1.0f;
        float gy = 2.0f * (yp + 0.5f) / (float)IMH - 1.0f;
        float x  = (gx + 1.0f) * ((float)IMW * 0.5f) - 0.5f;
        float y  = (gy + 1.0f) * ((float)IMH * 0.5f) - 0.5f;
        float x0 = floorf(x), y0 = floorf(y);
        wxs[s] = x - x0;
        wys[s] = y - y0;
        int xi = (int)x0, yi = (int)y0;
        xi = min(max(xi, 0), IMW - 2);
        yi = min(max(yi, 0), IMH - 2);
        off[s] = (yi * IMW + xi) * 16;
        if (s == 0) twoff = (yi * IMW + xi) * 4;
    }

    // ---- issue ALL scattered loads up front: 10 int4 gathers + twq ----
    const char* mapb = rec + (size_t)b * RECB;
    int4 L0[5], L1[5];
#pragma unroll
    for (int s = 0; s < 5; ++s) {
        L0[s] = *(const int4*)(mapb + off[s]);
        L1[s] = *(const int4*)(mapb + off[s] + 16);
    }
    const int twq = *(const int*)(twr + (size_t)b * TWB + twoff);

    float srcv[16];
    const float* srcb = src_feat + (size_t)b * CHN * HW + p;
#pragma unroll
    for (int c = 0; c < 16; ++c) srcv[c] = srcb[c * HW];

    const float* P2b = P2 + (size_t)b * 3 * HW;
    const float X = P2b[p], Y = P2b[HW + p], Z = P2b[2 * HW + p];
    const float wP  = weight[(size_t)b * HW + p];
    const float swP = src_w[(size_t)b * HW + p];

    // ---- latency fill: Jacobian rows + corner weights ----
    const float fx = calibK[b * 9 + 0];
    const float fy = calibK[b * 9 + 4];
    const float fxZ = fx / Z, fyZ = fy / Z;
    const float fxXZ2 = fxZ * X / Z;
    const float fyYZ2 = fyZ * Y / Z;
    float r0[6] = { fxZ, 0.0f, -fxXZ2, -fxXZ2 * Y, fx + fxXZ2 * X, -fxZ * Y };
    float r1[6] = { 0.0f, fyZ, -fyYZ2, -fy - fyYZ2 * Y, fyYZ2 * X, fyZ * X };

    float w00[5], w01[5], w10[5], w11[5];
#pragma unroll
    for (int s = 0; s < 5; ++s) {
        float wx = wxs[s], wy = wys[s];
        w00[s] = (1.0f - wx) * (1.0f - wy);
        w01[s] = wx * (1.0f - wy);
        w10[s] = (1.0f - wx) * wy;
        w11[s] = wx * wy;
    }

    float wtw;
    {
        const float wx = wxs[0], wy = wys[0];
        f32x2 wlo = __builtin_amdgcn_cvt_pk_f32_fp8(twq, false);
        f32x2 whi = __builtin_amdgcn_cvt_pk_f32_fp8(twq, true);
        wtw = wlo[0] * (1.0f - wx) * (1.0f - wy) + wlo[1] * wx * (1.0f - wy)
            + whi[0] * (1.0f - wx) * wy          + whi[1] * wx * wy;
    }
    const float w = swP * wtw * wP;

    // ---- decode fp4 + bilinear mix + moments ----
    // L0[s] = record(x0,y0)  = {p00.d0, p00.d1, p10.d0, p10.d1}
    // L1[s] = record(x0+1,y0)= {p01.d0, p01.d1, p11.d0, p11.d1}
    f32x2 SxxV = {0.f,0.f}, SxyV = {0.f,0.f}, SyyV = {0.f,0.f}, TxV = {0.f,0.f}, TyV = {0.f,0.f};
#define PAIRSTEP(H, K) {                                                          \
        f32x2 fsv[5];                                                             \
        _Pragma("unroll")                                                         \
        for (int s = 0; s < 5; ++s) {                                             \
            const int ad = (H) ? L0[s].y : L0[s].x;                               \
            const int bd = (H) ? L1[s].y : L1[s].x;                               \
            const int cd = (H) ? L0[s].w : L0[s].z;                               \
            const int dd = (H) ? L1[s].w : L1[s].z;                               \
            fsv[s] = __builtin_amdgcn_cvt_scalef32_pk_f32_fp4(ad, 1.0f, K) * w00[s] \
                   + __builtin_amdgcn_cvt_scalef32_pk_f32_fp4(bd, 1.0f, K) * w01[s] \
                   + __builtin_amdgcn_cvt_scalef32_pk_f32_fp4(cd, 1.0f, K) * w10[s] \
                   + __builtin_amdgcn_cvt_scalef32_pk_f32_fp4(dd, 1.0f, K) * w11[s]; \
        }                                                                         \
        const f32x2 sr = { srcv[(H) * 8 + 2 * (K)], srcv[(H) * 8 + 2 * (K) + 1] };\
        f32x2 resv = sr - fsv[0];                                                 \
        f32x2 gxv  = (fsv[1] - fsv[2]) * 0.5f;                                    \
        f32x2 gyv  = (fsv[3] - fsv[4]) * 0.5f;                                    \
        SxxV += gxv * gxv; SxyV += gxv * gyv; SyyV += gyv * gyv;                  \
        TxV  += resv * gxv; TyV += resv * gyv; }
    PAIRSTEP(0, 0) PAIRSTEP(0, 1) PAIRSTEP(0, 2) PAIRSTEP(0, 3)
    PAIRSTEP(1, 0) PAIRSTEP(1, 1) PAIRSTEP(1, 2) PAIRSTEP(1, 3)
#undef PAIRSTEP

    const float Sxx = SxxV[0] + SxxV[1];
    const float Sxy = SxyV[0] + SxyV[1];
    const float Syy = SyyV[0] + SyyV[1];
    const float Tx  = TxV[0]  + TxV[1];
    const float Ty  = TyV[0]  + TyV[1];

    const float Pm = w * Sxx, Qm = w * Sxy, Rm = w * Syy;
    const float tx = w * Tx,  ty = w * Ty;

    // ---- rank-2 H: H(k,l) = r0[k]*a[l] + r1[k]*c[l] ----
    float av[6], cv[6];
#pragma unroll
    for (int k = 0; k < 6; ++k) {
        av[k] = Pm * r0[k] + Qm * r1[k];
        cv[k] = Qm * r0[k] + Rm * r1[k];
    }

    // ---- 27 values: 4-step DPP row sum -> 4 LDS rows -> combine -> transposed store ----
    const int rrow = t >> 4;             // 0..3
    const bool wr  = (t & 15) == 15;

    int idx = 0;
#pragma unroll
    for (int k = 0; k < 6; ++k) {
#pragma unroll
        for (int l = 0; l < 6; ++l) {
            if (l < k) continue;
            float v = r0[k] * av[l] + r1[k] * cv[l];
            v = dpp_row_sum(v);
            if (wr) red[rrow][idx] = v;
            ++idx;
        }
    }
#pragma unroll
    for (int k = 0; k < 6; ++k) {
        float v = tx * r0[k] + ty * r1[k];
        v = dpp_row_sum(v);
        if (wr) red[rrow][21 + k] = v;
    }
    __syncthreads();
    if (t < NPART) {
        float s = red[0][t] + red[1][t] + red[2][t] + red[3][t];
        partials[((size_t)b * NPART + t) * NSLOT + blk] = s;
    }
}

// ---------------- kernel 2: double reduce (transposed, coalesced) + solve + se3_exp ----------------
__global__ __launch_bounds__(256) void gn_solve(
    const float* __restrict__ partials,  // (B, NPART, NSLOT)
    const float* __restrict__ poses,
    float* __restrict__ out)
{
    const int b = blockIdx.x;
    const int t = threadIdx.x;
    __shared__ double dsum[8][NPART];
    __shared__ double sums[NPART];

    if (t < 216) {
        const int col = t % NPART;
        const int g   = t / NPART;       // 0..7
        const float* pb = partials + ((size_t)b * NPART + col) * NSLOT;
        double s = 0.0;
        for (int j = g; j < NSLOT; j += 8)
            s += (double)pb[j];
        dsum[g][col] = s;
    }
    __syncthreads();
    if (t < NPART) {
        double s = 0.0;
#pragma unroll
        for (int g = 0; g < 8; ++g) s += dsum[g][t];
        sums[t] = s;
    }
    __syncthreads();
    if (t != 0) return;

    double A[6][7];
    {
        int idx = 0;
        for (int k = 0; k < 6; ++k)
            for (int l = k; l < 6; ++l) {
                A[k][l] = sums[idx];
                A[l][k] = sums[idx];
                ++idx;
            }
        for (int k = 0; k < 6; ++k) A[k][6] = sums[21 + k];
    }
    for (int col = 0; col < 6; ++col) {
        int piv = col; double mx = fabs(A[col][col]);
        for (int rr = col + 1; rr < 6; ++rr) {
            double v = fabs(A[rr][col]);
            if (v > mx) { mx = v; piv = rr; }
        }
        if (piv != col)
            for (int j = col; j < 7; ++j) { double tmp = A[col][j]; A[col][j] = A[piv][j]; A[piv][j] = tmp; }
        double d = A[col][col];
        for (int rr = col + 1; rr < 6; ++rr) {
            double f = A[rr][col] / d;
            for (int j = col; j < 7; ++j) A[rr][j] -= f * A[col][j];
        }
    }
    double x[6];
    for (int i = 5; i >= 0; --i) {
        double s = A[i][6];
        for (int j = i + 1; j < 6; ++j) s -= A[i][j] * x[j];
        x[i] = s / A[i][i];
    }

    const double rho[3] = { x[0], x[1], x[2] };
    const double phi[3] = { x[3], x[4], x[5] };
    const double th2 = phi[0]*phi[0] + phi[1]*phi[1] + phi[2]*phi[2];
    const bool small = th2 < 1e-8;
    const double th2s = small ? 1.0 : th2;
    const double th = sqrt(th2s);
    const double Ac = small ? 1.0 - th2 / 6.0   : sin(th) / th;
    const double Bc = small ? 0.5 - th2 / 24.0  : (1.0 - cos(th)) / th2s;
    const double Cc = small ? 1.0/6.0 - th2/120.0 : (th - sin(th)) / (th2s * th);
    const double Kh[3][3] = { { 0.0, -phi[2],  phi[1] },
                              {  phi[2], 0.0, -phi[0] },
                              { -phi[1],  phi[0], 0.0 } };
    double K2[3][3];
    for (int i = 0; i < 3; ++i)
        for (int j = 0; j < 3; ++j) {
            double s = 0.0;
            for (int k = 0; k < 3; ++k) s += Kh[i][k] * Kh[k][j];
            K2[i][j] = s;
        }
    double T[4][4];
    for (int i = 0; i < 3; ++i)
        for (int j = 0; j < 3; ++j) {
            double I = (i == j) ? 1.0 : 0.0;
            T[i][j] = I + Ac * Kh[i][j] + Bc * K2[i][j];
        }
    for (int i = 0; i < 3; ++i) {
        double s = 0.0;
        for (int j = 0; j < 3; ++j) {
            double I = (i == j) ? 1.0 : 0.0;
            double V = I + Bc * Kh[i][j] + Cc * K2[i][j];
            s += V * rho[j];
        }
        T[i][3] = s;
    }
    T[3][0] = 0.0; T[3][1] = 0.0; T[3][2] = 0.0; T[3][3] = 1.0;

    const float* pz = poses + b * 16;
    for (int i = 0; i < 4; ++i)
        for (int j = 0; j < 4; ++j) {
            double s = 0.0;
            for (int k = 0; k < 4; ++k) s += T[i][k] * (double)pz[k * 4 + j];
            out[b * 16 + i * 4 + j] = (float)s;
        }
    for (int k = 0; k < 6; ++k)
        out[BATCH * 16 + b * 6 + k] = (float)x[k];
}

extern "C" void kernel_launch(void* const* d_in, const int* in_sizes, int n_in,
                              void* d_out, int out_size, void* d_ws, size_t ws_size,
                              hipStream_t stream) {
    const float* poses    = (const float*)d_in[0];
    const float* calibK   = (const float*)d_in[1];
    const float* p2       = (const float*)d_in[2];
    const float* P2       = (const float*)d_in[3];
    const float* weight   = (const float*)d_in[4];
    const float* src_feat = (const float*)d_in[5];
    const float* tgt_feat = (const float*)d_in[6];
    const float* src_w    = (const float*)d_in[7];
    const float* tgt_w    = (const float*)d_in[8];
    float* out = (float*)d_out;

    char*  rec      = (char*)d_ws;                               // 16*RECB = 7.9 MB
    char*  twr      = rec + (size_t)BATCH * RECB;                // 16*TWB  = 2.0 MB
    float* partials = (float*)(twr + (size_t)BATCH * TWB);       // 0.83 MB (total 10.7 MB)

    hipLaunchKernelGGL(build_maps, dim3(HW / 256, BATCH), dim3(256), 0, stream,
                       tgt_feat, tgt_w, rec, twr);
    hipLaunchKernelGGL(gn_accum, dim3(NSLOT * BATCH), dim3(PPB), 0, stream,
                       p2, P2, calibK, weight, src_feat, src_w, twr, rec, partials);
    hipLaunchKernelGGL(gn_solve, dim3(BATCH), dim3(256), 0, stream,
                       partials, poses, out);
}